// Round 6
// baseline (758.470 us; speedup 1.0000x reference)
//
#include <hip/hip_runtime.h>
#include <stdint.h>

// Binary conv 3x3 s1 p1 — XNOR-popcount.
//   prep:  zero halo + pack w + pack x  (one kernel, grid-stride)
//   bconv3: persistent blocks, one (n, o-block-of-8) per block, 13 pixel chunks.
//           Weights in LDS (576 words), read as same-address b128 broadcast.
//           out = corr[cfg] - 2 * sum_{9 taps,8 words} popc(x ^ w)
//           corr[cfg][o] = 256*nvalid + 2*sum_{invalid taps} popc(w_tap)

#define N_BATCH 32
#define C_IN    256
#define HH      56
#define WW_     56
#define HW      (HH * WW_)   // 3136
#define C_OUT   256
#define WORDS   8
#define TAPS    9
#define PH      58
#define PW      58
#define GRID_PREP 1024

// ---- kernel 1: halo zero + pack_w + pack_x, all grid-stride ----
__global__ __launch_bounds__(256) void prep_kernel(const float* __restrict__ x,
                                                   const float* __restrict__ wt,
                                                   uint32_t* __restrict__ xp,
                                                   uint32_t* __restrict__ wp) {
    const int T = GRID_PREP * 256;
    const int tid0 = blockIdx.x * 256 + threadIdx.x;

    // (a) zero the padded halo (disjoint from interior pack writes)
    for (int i = tid0; i < N_BATCH * 228 * WORDS; i += T) {
        int n = i / (228 * WORDS);
        int r = i % (228 * WORDS);
        int pos = r / WORDS, word = r % WORDS;
        int hh, ww;
        if (pos < 58)       { hh = 0;             ww = pos; }
        else if (pos < 116) { hh = 57;            ww = pos - 58; }
        else if (pos < 172) { hh = pos - 116 + 1; ww = 0; }
        else                { hh = pos - 172 + 1; ww = 57; }
        xp[(((size_t)n * PH + hh) * PW + ww) * WORDS + word] = 0u;
    }

    // (b) pack weights -> wp[o][tap][word]
    for (int i = tid0; i < C_OUT * TAPS * WORDS; i += T) {
        int o = i / (TAPS * WORDS);
        int r = i % (TAPS * WORDS);
        int tap = r / WORDS, j = r % WORDS;
        uint32_t bits = 0;
#pragma unroll
        for (int ii = 0; ii < 32; ++ii) {
            float v = wt[((size_t)(o * C_IN + j * 32 + ii)) * TAPS + tap];
            bits |= (v > 0.0f ? 1u : 0u) << ii;
        }
        wp[i] = bits;
    }

    // (c) pack x -> padded xp interior
    for (int i = tid0; i < N_BATCH * HW * WORDS; i += T) {
        int s = i % HW;
        int t = i / HW;
        int n = t % N_BATCH;
        int word = t / N_BATCH;
        int h = s / WW_, w2 = s % WW_;
        const float* px = x + ((size_t)(n * C_IN + word * 32)) * HW + s;
        uint32_t bits = 0;
#pragma unroll
        for (int ii = 0; ii < 32; ++ii) {
            float v = px[(size_t)ii * HW];          // coalesced across lanes
            bits |= (v > 0.0f ? 1u : 0u) << ii;
        }
        xp[(((size_t)n * PH + (h + 1)) * PW + (w2 + 1)) * WORDS + word] = bits;
    }
}

// ---- kernel 2: persistent-block xnor-popcount conv ----
// grid = 1024 blocks = all (n, ob) pairs; XCD-aware mapping: blocks on the
// same XCD (b%8 under round-robin) share 4 consecutive n -> 1.7 MB L2 set.
__global__ __launch_bounds__(256, 4) void bconv3_kernel(const uint32_t* __restrict__ xp,
                                                        const uint32_t* __restrict__ wp,
                                                        float* __restrict__ out) {
    __shared__ __align__(16) uint32_t wlds[8 * TAPS * WORDS];  // 576 words
    __shared__ int clds[9][8];                                 // corr[cfg][o_local]

    const int tid = threadIdx.x;
    const int b = blockIdx.x;                   // 0..1023
    const int n  = (b & 7) * 4 + (b >> 8);      // 4 n's per XCD slot
    const int ob = (b >> 3) & 31;
    const int o_base = ob * 8;

    // stage this o-block's packed weights (576 contiguous words) into LDS
    if (tid < 144)
        reinterpret_cast<uint4*>(wlds)[tid] =
            reinterpret_cast<const uint4*>(wp + (size_t)o_base * TAPS * WORDS)[tid];

    // border-correction table: thread per local o
    if (tid < 8) {
        int pc[TAPS];
#pragma unroll
        for (int tap = 0; tap < TAPS; ++tap) {
            int c = 0;
#pragma unroll
            for (int j = 0; j < WORDS; ++j)
                c += __popc(wp[((size_t)(o_base + tid) * TAPS + tap) * WORDS + j]);
            pc[tap] = c;
        }
#pragma unroll
        for (int hp = 0; hp < 3; ++hp) {
#pragma unroll
            for (int wq = 0; wq < 3; ++wq) {
                int nv = (hp == 1 ? 3 : 2) * (wq == 1 ? 3 : 2);
                int sinv = 0;
#pragma unroll
                for (int kh = 0; kh < 3; ++kh)
#pragma unroll
                    for (int kw = 0; kw < 3; ++kw) {
                        bool inv = (kh == 0 && hp == 0) || (kh == 2 && hp == 2) ||
                                   (kw == 0 && wq == 0) || (kw == 2 && wq == 2);
                        if (inv) sinv += pc[kh * 3 + kw];
                    }
                clds[hp * 3 + wq][tid] = 256 * nv + 2 * sinv;
            }
        }
    }
    __syncthreads();

    const uint32_t* xpn = xp + (size_t)n * PH * PW * WORDS;

#pragma unroll 1
    for (int chunk = 0; chunk < 13; ++chunk) {
        int s = chunk * 256 + tid;
        if (s < HW) {
            int h = s / WW_;
            int w2 = s - h * WW_;

            int acc[8];
#pragma unroll
            for (int lo = 0; lo < 8; ++lo) acc[lo] = 0;

#pragma unroll
            for (int r = 0; r < 3; ++r) {
                // padded row of the (r-1) tap row: in-bounds by construction
                const uint32_t* pr = xpn + ((size_t)(h + r) * PW + w2) * WORDS;
#pragma unroll
                for (int t = 0; t < 3; ++t) {
                    uint4 a = *reinterpret_cast<const uint4*>(pr + t * WORDS);
                    uint4 bq = *reinterpret_cast<const uint4*>(pr + t * WORDS + 4);
                    uint32_t xw[8] = {a.x, a.y, a.z, a.w, bq.x, bq.y, bq.z, bq.w};
                    int tap = r * 3 + t;
#pragma unroll
                    for (int lo = 0; lo < 8; ++lo) {
                        // same address across all 64 lanes -> conflict-free broadcast
                        const uint32_t* pwl = wlds + (lo * TAPS + tap) * WORDS;
                        uint4 w0 = *reinterpret_cast<const uint4*>(pwl);
                        uint4 w1 = *reinterpret_cast<const uint4*>(pwl + 4);
                        acc[lo] += __popc(xw[0] ^ w0.x) + __popc(xw[1] ^ w0.y) +
                                   __popc(xw[2] ^ w0.z) + __popc(xw[3] ^ w0.w) +
                                   __popc(xw[4] ^ w1.x) + __popc(xw[5] ^ w1.y) +
                                   __popc(xw[6] ^ w1.z) + __popc(xw[7] ^ w1.w);
                    }
                }
            }

            int hp = (h == 0) ? 0 : ((h == HH - 1) ? 2 : 1);
            int wq = (w2 == 0) ? 0 : ((w2 == WW_ - 1) ? 2 : 1);
            int cfgb = hp * 3 + wq;
#pragma unroll
            for (int lo = 0; lo < 8; ++lo) {
                out[((size_t)(n * C_OUT + o_base + lo)) * HW + s] =
                    (float)(clds[cfgb][lo] - 2 * acc[lo]);
            }
        }
    }
}

extern "C" void kernel_launch(void* const* d_in, const int* in_sizes, int n_in,
                              void* d_out, int out_size, void* d_ws, size_t ws_size,
                              hipStream_t stream) {
    const float* x = (const float*)d_in[0];
    const float* w = (const float*)d_in[1];
    float* out = (float*)d_out;

    uint32_t* xp = (uint32_t*)d_ws;                         // 32*58*58*8 = 861184 u32
    uint32_t* wp = xp + (size_t)N_BATCH * PH * PW * WORDS;  // 18432 u32

    prep_kernel<<<dim3(GRID_PREP), 256, 0, stream>>>(x, w, xp, wp);
    bconv3_kernel<<<dim3(1024), 256, 0, stream>>>(xp, wp, out);
}

// Round 7
// 254.155 us; speedup vs baseline: 2.9843x; 2.9843x over previous
//
#include <hip/hip_runtime.h>
#include <stdint.h>

// Binary conv 3x3 s1 p1 via i8 MFMA implicit GEMM.
//   M = o (256), N = px (3136/n), K = 9 taps * 256 c = 2304, i8 operands in {+1,-1} (0 for halo).
//   Padded taps contribute exactly 0 (x unpacked to 0 bytes) -> no correction table.
//   prep_x: pack sign bits  xp[n][58][58][8 words]   (interior only; halo never consumed)
//   prep_w: w -> wq i8 {+1,-1}, layout [o][k], chunk-swizzled within each 128B row:
//           phys_chunk = (k>>4 & 7) ^ (o & 7)  (bank-conflict-free LDS reads, linear staging)
//   bgemm:  block = (px-tile 128, o-tile 128, n); K-chunks of 128, LDS double-buffered.
//           wave-tile 64x64 via 2x2 v_mfma_i32_32x32x32_i8.

typedef int i32x4 __attribute__((ext_vector_type(4)));
typedef int i32x16 __attribute__((ext_vector_type(16)));
typedef unsigned int u32;

#define N_BATCH 32
#define C_IN 256
#define C_OUT 256
#define HH 56
#define WW_ 56
#define HW 3136
#define PH 58
#define PW 58
#define WORDS 8
#define KD 576              // dwords per o-row of wq (2304 i8)

// ---- bit-nibble -> 4 sign bytes {1 -> 0x01, 0 -> 0xFF}, or 0x00 if tbl==0 (halo) ----
static __device__ __forceinline__ u32 expand4(u32 srcw, int sh, u32 tbl) {
    u32 u = (srcw >> sh) & 0xFu;
    u32 sp = u;
    sp |= u << 7;
    sp |= u << 14;
    sp |= u << 21;
    sp &= 0x01010101u;       // byte i = bit i of nibble
#if __has_builtin(__builtin_amdgcn_perm)
    return __builtin_amdgcn_perm(0u, tbl, sp);   // sel byte 0/1 -> tbl byte {0xFF,0x01}; tbl=0 -> 0
#else
    u32 r = 0;
#pragma unroll
    for (int i = 0; i < 4; ++i) {
        u32 bit = (sp >> (8 * i)) & 1u;
        u32 b = (tbl == 0u) ? 0u : (bit ? 0x01u : 0xFFu);
        r |= b << (8 * i);
    }
    return r;
#endif
}

// ---- pack x sign bits -> padded xp ----
__global__ __launch_bounds__(256) void prep_x(const float* __restrict__ x,
                                              u32* __restrict__ xp) {
    int sx = blockIdx.x * 64 + threadIdx.x;          // 0..3135 (grid.x=49, block.x=64)
    int word = blockIdx.y * 4 + threadIdx.y;         // 0..7    (grid.y=2,  block.y=4)
    int n = blockIdx.z;
    int h = sx / 56, w2 = sx - h * 56;
    const float* px = x + ((size_t)(n * C_IN + word * 32)) * HW + sx;
    u32 bits = 0;
#pragma unroll
    for (int i = 0; i < 32; ++i)
        bits |= (px[(size_t)i * HW] > 0.0f ? 1u : 0u) << i;
    xp[(((size_t)n * PH + (h + 1)) * PW + (w2 + 1)) * WORDS + word] = bits;
}

// ---- w -> i8 {+1,-1}, [o][k] with baked chunk swizzle ----
__global__ __launch_bounds__(256) void prep_w(const float* __restrict__ wt,
                                              u32* __restrict__ wq) {
    int d = blockIdx.x * 256 + threadIdx.x;          // 0..147455
    int o = d / KD;
    int kq = d - o * KD;
    int k = kq * 4;                                  // logical k of byte 0
    int tap = k >> 8;                                // k/256
    int c = k & 255;
    const float* ws = wt + ((size_t)o * C_IN + c) * 9 + tap;   // OIHW: stride over c = 9 floats
    u32 r = 0;
#pragma unroll
    for (int i = 0; i < 4; ++i) {
        u32 b = (ws[(size_t)i * 9] > 0.0f) ? 0x01u : 0xFFu;
        r |= b << (8 * i);
    }
    int chunk = (k >> 4) & 7;
    int pchunk = chunk ^ (o & 7);
    int gk = (k & ~127) | (pchunk << 4) | (k & 15);  // swizzled byte position
    wq[(size_t)o * KD + (gk >> 2)] = r;
}

// ---- implicit GEMM ----
__global__ __launch_bounds__(256, 2) void bgemm(const u32* __restrict__ xp,
                                                const u32* __restrict__ wq,
                                                float* __restrict__ out) {
    __shared__ __align__(16) u32 Wl[2][128 * 32];    // [buf][row o][128B k-chunk] 16 KB each
    __shared__ __align__(16) u32 Xl[2][128 * 32];    // [buf][row px][128B]       16 KB each

    const int tid = threadIdx.x;
    const int l = tid & 63;
    const int wave = tid >> 6;
    const int wm = wave >> 1, wn = wave & 1;         // 2x2 wave grid over (o, px)
    const int la = l & 31, lg = l >> 5;

    const int pxb = blockIdx.x;                      // 0..24
    const int ob = blockIdx.y;                       // 0..1
    const int n = blockIdx.z;                        // 0..31

    // --- X staging coords (thread-constant) ---
    const int px_l = tid >> 1;                       // 0..127
    const int hf = tid & 1;                          // which 64-bit half of the K-128 chunk
    int px_g = pxb * 128 + px_l;
    if (px_g > HW - 1) px_g = HW - 1;                // clamp (cols discarded at store)
    const int ih = px_g / 56;
    const int iw = px_g - ih * 56;

    // --- W staging assignment: thread -> (4 rows, 1 chunk) ---
    const int wc = tid & 7;                          // chunk 0..7
    const int wo0 = (tid >> 3) << 2;                 // rows wo0..wo0+3
    const u32* wbase = wq + ((size_t)(ob * 128 + wo0)) * KD + wc * 4;

    i32x16 acc00 = {0}, acc01 = {0}, acc10 = {0}, acc11 = {0};

    const int rowA0 = wm * 64 + la;
    const int rowB0 = wn * 64 + la;

    u32 xd0, xd1, xtbl;
    i32x4 wv0, wv1, wv2, wv3;

    auto LOAD = [&](int kc) {
        int tap = kc >> 1, cc = kc & 1;
        int rr = tap / 3, tt = tap - rr * 3;
        int hp = ih + rr, wp2 = iw + tt;             // padded coords 0..57
        bool halo = (hp == 0) | (hp == PH - 1) | (wp2 == 0) | (wp2 == PW - 1);
        const u32* src = xp + (((size_t)n * PH + hp) * PW + wp2) * WORDS + cc * 4 + hf * 2;
        xd0 = src[0];
        xd1 = src[1];
        xtbl = halo ? 0u : 0x000001FFu;
        const u32* ws = wbase + (size_t)kc * 32;
        wv0 = *(const i32x4*)(ws);
        wv1 = *(const i32x4*)(ws + KD);
        wv2 = *(const i32x4*)(ws + 2 * KD);
        wv3 = *(const i32x4*)(ws + 3 * KD);
    };

    auto WRITE = [&](int buf) {
        // X: 16 out-dwords = logical chunks hf*4 + 0..3
        u32 outd[16];
#pragma unroll
        for (int q = 0; q < 16; ++q)
            outd[q] = expand4((q < 8) ? xd0 : xd1, (q & 7) * 4, xtbl);
#pragma unroll
        for (int w = 0; w < 4; ++w) {
            int phys = ((hf * 4 + w) ^ (px_l & 7)) * 4;
            *(i32x4*)&Xl[buf][px_l * 32 + phys] = *(const i32x4*)&outd[w * 4];
        }
        // W: linear copy (swizzle baked into global layout)
        *(i32x4*)&Wl[buf][(wo0 + 0) * 32 + wc * 4] = wv0;
        *(i32x4*)&Wl[buf][(wo0 + 1) * 32 + wc * 4] = wv1;
        *(i32x4*)&Wl[buf][(wo0 + 2) * 32 + wc * 4] = wv2;
        *(i32x4*)&Wl[buf][(wo0 + 3) * 32 + wc * 4] = wv3;
    };

    auto COMPUTE = [&](int buf) {
#pragma unroll
        for (int kk = 0; kk < 4; ++kk) {
            int phys = (((kk * 2 + lg) ^ (la & 7)) << 2);
            i32x4 a0 = *(const i32x4*)&Wl[buf][(rowA0)      * 32 + phys];
            i32x4 a1 = *(const i32x4*)&Wl[buf][(rowA0 + 32) * 32 + phys];
            i32x4 b0 = *(const i32x4*)&Xl[buf][(rowB0)      * 32 + phys];
            i32x4 b1 = *(const i32x4*)&Xl[buf][(rowB0 + 32) * 32 + phys];
            acc00 = __builtin_amdgcn_mfma_i32_32x32x32_i8(a0, b0, acc00, 0, 0, 0);
            acc01 = __builtin_amdgcn_mfma_i32_32x32x32_i8(a0, b1, acc01, 0, 0, 0);
            acc10 = __builtin_amdgcn_mfma_i32_32x32x32_i8(a1, b0, acc10, 0, 0, 0);
            acc11 = __builtin_amdgcn_mfma_i32_32x32x32_i8(a1, b1, acc11, 0, 0, 0);
        }
    };

    // prologue
    LOAD(0);
    WRITE(0);
    __syncthreads();

    int cur = 0;
#pragma unroll 1
    for (int kc = 0; kc < 18; ++kc) {
        if (kc < 17) LOAD(kc + 1);       // issue global reads early (hide under MFMA)
        COMPUTE(cur);
        if (kc < 17) WRITE(cur ^ 1);
        __syncthreads();
        cur ^= 1;
    }

    // epilogue: C[o][px], col = lane&31 = px (contiguous), row = (reg&3)+8*(reg>>2)+4*(lane>>5)
    const int og0 = ob * 128 + wm * 64;
    const int pxg0 = pxb * 128 + wn * 64;
    float* outn = out + (size_t)n * C_OUT * HW;

    auto STORE = [&](const i32x16& a, int obase, int pbase) {
        if (pbase >= HW) return;                      // tile fully out of range (HW % 32 == 0)
        int px = pbase + la;
#pragma unroll
        for (int r = 0; r < 16; ++r) {
            int orow = obase + (r & 3) + 8 * (r >> 2) + 4 * lg;
            outn[(size_t)orow * HW + px] = (float)a[r];
        }
    };
    STORE(acc00, og0,      pxg0);
    STORE(acc01, og0,      pxg0 + 32);
    STORE(acc10, og0 + 32, pxg0);
    STORE(acc11, og0 + 32, pxg0 + 32);
}

extern "C" void kernel_launch(void* const* d_in, const int* in_sizes, int n_in,
                              void* d_out, int out_size, void* d_ws, size_t ws_size,
                              hipStream_t stream) {
    const float* x = (const float*)d_in[0];
    const float* w = (const float*)d_in[1];
    float* out = (float*)d_out;

    u32* xp = (u32*)d_ws;                            // 32*58*58*8 = 861184 dw (3.44 MB)
    u32* wq = xp + (size_t)N_BATCH * PH * PW * WORDS; // 147456 dw (0.59 MB) -> 4.03 MB total

    prep_x<<<dim3(49, 2, 32), dim3(64, 4), 0, stream>>>(x, xp);
    prep_w<<<dim3(576), dim3(256), 0, stream>>>(w, wq);
    bgemm<<<dim3(25, 2, 32), dim3(256), 0, stream>>>(xp, wq, out);
}